// Round 13
// baseline (819.213 us; speedup 1.0000x reference)
//
#include <hip/hip_runtime.h>

#define HID 128

typedef __attribute__((ext_vector_type(8))) short short8;
typedef __attribute__((ext_vector_type(8))) unsigned short ushort8v;
typedef __attribute__((ext_vector_type(4))) float floatx4;
typedef __attribute__((ext_vector_type(4))) unsigned short ushort4v;

__device__ __forceinline__ unsigned short f2bf(float f) {
    unsigned u = __builtin_bit_cast(unsigned, f);
    u += 0x7FFF + ((u >> 16) & 1);           // RNE
    return (unsigned short)(u >> 16);
}
__device__ __forceinline__ float bf2f(unsigned short s) {
    unsigned u = ((unsigned)s) << 16;
    return __builtin_bit_cast(float, u);
}

// ---------------- merged fill: dis (deg accumulator) + indeg ----------------
__global__ void fillrd_kernel(float* __restrict__ dis, int* __restrict__ indeg, int N)
{
    int i = blockIdx.x * 256 + threadIdx.x;
    if (i < N) { dis[i] = 0.f; indeg[i] = 0; }
}

// ---------------- diagnostic ----------------
__global__ void diag_kernel(float* __restrict__ out, long n, float val)
{
    long i = (long)blockIdx.x * blockDim.x + threadIdx.x;
    if (i < n) out[i] = val;
}

// ---------------- merged tables ----------------
__global__ __launch_bounds__(256) void tables_kernel(
    const float* __restrict__ conv_W, unsigned short* __restrict__ Wb,
    const float* __restrict__ lin_W, unsigned short* __restrict__ linWb,
    const float* __restrict__ bond_emb, float* __restrict__ comb,
    const float* __restrict__ gamma, const float* __restrict__ beta,
    const float* __restrict__ mean, const float* __restrict__ var,
    float* __restrict__ bnsc, float* __restrict__ bnsh)
{
    int blk = blockIdx.x;
    int tid = threadIdx.x;
    if (blk < 64) {
        int i = blk * 256 + tid;
        Wb[i] = f2bf(conv_W[i]);
    } else if (blk < 128) {
        int i = (blk - 64) * 256 + tid;
        linWb[i] = f2bf(lin_W[i]);
    } else if (blk < 158) {
        int i = (blk - 128) * 2 + (tid >> 7);
        int c = tid & 127;
        int a0 = i / 12, a1 = (i % 12) / 2, a2 = i % 2;
        comb[i * HID + c] = bond_emb[a0 * HID + c] + bond_emb[(5 + a1) * HID + c]
                          + bond_emb[(11 + a2) * HID + c];
    } else if (tid < HID) {
        float sc = gamma[tid] * rsqrtf(var[tid] + 1e-5f);
        bnsc[tid] = sc;
        bnsh[tid] = beta[tid] - mean[tid] * sc;
    }
}

// ---------------- merged degree histograms ----------------
__global__ void hist_kernel(const int* __restrict__ ei, float* __restrict__ dis,
                            int* __restrict__ indeg, int E)
{
    for (int e = blockIdx.x * blockDim.x + threadIdx.x; e < E; e += gridDim.x * blockDim.x) {
        atomicAdd(&dis[ei[e]], 1.f);
        atomicAdd(&indeg[ei[E + e]], 1);
    }
}

__global__ void fdeg_kernel(float* __restrict__ dis, int N)
{
    int n = blockIdx.x * blockDim.x + threadIdx.x;
    if (n < N) dis[n] = rsqrtf(dis[n] + 1.f);
}

// ---------------- CSR scan chain ----------------
__global__ __launch_bounds__(256) void bsum_kernel(
    const int* __restrict__ indeg, int* __restrict__ partial, int N)
{
    __shared__ int s[256];
    int i = blockIdx.x * 256 + threadIdx.x;
    s[threadIdx.x] = (i < N) ? indeg[i] : 0;
    __syncthreads();
    for (int d = 128; d > 0; d >>= 1) {
        if (threadIdx.x < d) s[threadIdx.x] += s[threadIdx.x + d];
        __syncthreads();
    }
    if (threadIdx.x == 0) partial[blockIdx.x] = s[0];
}

__global__ __launch_bounds__(256) void scan1_kernel(
    const int* __restrict__ partial, int* __restrict__ offs,
    int* __restrict__ ptr, int B, int N)
{
    __shared__ int s[256];
    __shared__ int carry_s;
    int tid = threadIdx.x;
    if (tid == 0) carry_s = 0;
    __syncthreads();
    for (int base = 0; base < B; base += 256) {
        int i = base + tid;
        int v = (i < B) ? partial[i] : 0;
        s[tid] = v;
        __syncthreads();
        for (int d = 1; d < 256; d <<= 1) {
            int t = (tid >= d) ? s[tid - d] : 0;
            __syncthreads();
            s[tid] += t;
            __syncthreads();
        }
        int carry = carry_s;
        if (i < B) offs[i] = carry + s[tid] - v;
        __syncthreads();
        if (tid == 0) carry_s = carry + s[255];
        __syncthreads();
    }
    if (tid == 0) ptr[N] = carry_s;
}

__global__ __launch_bounds__(256) void scan2_kernel(
    const int* __restrict__ indeg, const int* __restrict__ offs,
    int* __restrict__ ptr, int* __restrict__ cursor, int N)
{
    __shared__ int s[256];
    int tid = threadIdx.x;
    int i = blockIdx.x * 256 + tid;
    int v = (i < N) ? indeg[i] : 0;
    s[tid] = v;
    __syncthreads();
    for (int d = 1; d < 256; d <<= 1) {
        int t = (tid >= d) ? s[tid - d] : 0;
        __syncthreads();
        s[tid] += t;
        __syncthreads();
    }
    if (i < N) {
        int ex = offs[blockIdx.x] + s[tid] - v;
        ptr[i] = ex;
        cursor[i] = ex;
    }
}

// ---------------- CSR fill: packed edge record ----------------
__global__ void fillcsr_kernel(const int* __restrict__ ei, const int* __restrict__ attr,
                               const float* __restrict__ dis, int* __restrict__ cursor,
                               int2* __restrict__ edata, int E)
{
    for (int e = blockIdx.x * blockDim.x + threadIdx.x; e < E; e += gridDim.x * blockDim.x) {
        int r   = ei[e];
        int col = ei[E + e];
        int pos = atomicAdd(&cursor[col], 1);
        int ci  = attr[e * 3] * 12 + attr[e * 3 + 1] * 2 + attr[e * 3 + 2];
        float nrm = dis[r] * dis[col];
        int2 ed;
        ed.x = r;
        ed.y = ci | ((int)f2bf(nrm) << 16);
        edata[pos] = ed;
    }
}

// ---------------- graph boundaries ----------------
__global__ void gptr_kernel(const int* __restrict__ batch, int* __restrict__ gptr,
                            int N, int G)
{
    int n = blockIdx.x * blockDim.x + threadIdx.x;
    if (n >= N) return;
    int b = batch[n];
    int bp = (n == 0) ? -1 : batch[n - 1];
    for (int g = bp + 1; g <= b; ++g) gptr[g] = n;
    if (n == N - 1)
        for (int g = b + 1; g <= G; ++g) gptr[g] = N;
}

// ---------------- shared agg body ----------------
template<bool FIRST>
__device__ __forceinline__ ushort8v agg_node(
    long n, int c, const int* __restrict__ ptr, const int2* __restrict__ edata,
    const float* __restrict__ comb, const float* __restrict__ dis,
    const float* __restrict__ root, const float* __restrict__ bnsc,
    const float* __restrict__ bnsh, const unsigned short* __restrict__ zb,
    const unsigned short* __restrict__ hb, float fi)
{
    ushort8v zv = *reinterpret_cast<const ushort8v*>(zb + n * HID + c);
    ushort8v hv;
    if constexpr (!FIRST) hv = *reinterpret_cast<const ushort8v*>(hb + n * HID + c);
    float di = dis[n];
    float rd = di * di;
    float acc[8];
#pragma unroll
    for (int j = 0; j < 8; ++j) acc[j] = fmaxf(bf2f(zv[j]) + root[c + j], 0.f) * rd;

    int jb = ptr[n], je = ptr[n + 1];
    int j2 = jb;
    for (; j2 + 1 < je; j2 += 2) {
        int2 e0 = edata[j2];
        int2 e1 = edata[j2 + 1];
        ushort8v z0 = *reinterpret_cast<const ushort8v*>(zb + (long)e0.x * HID + c);
        ushort8v z1 = *reinterpret_cast<const ushort8v*>(zb + (long)e1.x * HID + c);
        const float* c0 = comb + (e0.y & 0xFF) * HID + c;
        const float* c1 = comb + (e1.y & 0xFF) * HID + c;
        float n0 = bf2f((unsigned short)(((unsigned)e0.y) >> 16));
        float n1 = bf2f((unsigned short)(((unsigned)e1.y) >> 16));
#pragma unroll
        for (int j = 0; j < 8; ++j) {
            acc[j] += fmaxf(bf2f(z0[j]) + c0[j], 0.f) * n0;
            acc[j] += fmaxf(bf2f(z1[j]) + c1[j], 0.f) * n1;
        }
    }
    if (j2 < je) {
        int2 e0 = edata[j2];
        ushort8v z0 = *reinterpret_cast<const ushort8v*>(zb + (long)e0.x * HID + c);
        const float* c0 = comb + (e0.y & 0xFF) * HID + c;
        float n0 = bf2f((unsigned short)(((unsigned)e0.y) >> 16));
#pragma unroll
        for (int j = 0; j < 8; ++j) acc[j] += fmaxf(bf2f(z0[j]) + c0[j], 0.f) * n0;
    }

    ushort8v o;
#pragma unroll
    for (int j = 0; j < 8; ++j) {
        float t = fmaxf(acc[j], 0.f) * bnsc[c + j] + bnsh[c + j];
        float h;
        if constexpr (FIRST) h = t;
        else h = fi * bf2f(hv[j]) + (1.f - fi) * t;
        o[j] = f2bf(h);
    }
    return o;
}

// ---------------- standalone agg (high-occupancy gather loop) ----------------
template<bool FIRST>
__global__ __launch_bounds__(256) void agg_kernel(
    const int* __restrict__ ptr, const int2* __restrict__ edata,
    const float* __restrict__ comb, const float* __restrict__ dis,
    const float* __restrict__ root, const float* __restrict__ bnsc,
    const float* __restrict__ bnsh, const unsigned short* __restrict__ zb,
    unsigned short* __restrict__ hb, float fi, int N)
{
    long n = (long)blockIdx.x * 16 + (threadIdx.x >> 4);
    if (n >= N) return;
    int c = (threadIdx.x & 15) * 8;
    ushort8v o = agg_node<FIRST>(n, c, ptr, edata, comb, dis, root, bnsc, bnsh, zb, hb, fi);
    *reinterpret_cast<ushort8v*>(hb + n * HID + c) = o;
}

// ---------------- z = h @ W^T + b  (64-row tile: 16.9 KB LDS, 1 m-tile/wave) --
__global__ __launch_bounds__(256) void gemm_kernel(
    const unsigned short* __restrict__ hb, const unsigned short* __restrict__ Wb,
    const float* __restrict__ bias, unsigned short* __restrict__ zb, int N)
{
    __shared__ unsigned short st[64][132];    // +4 pad
    int tid = threadIdx.x;
    int wave = tid >> 6;
    int lane = tid & 63;
    int l15 = lane & 15;
    int q = lane >> 4;
    long base = (long)blockIdx.x * 64;

    short8 a[4];
    {
        long rl = base + wave * 16 + l15;
        if (rl > (long)N - 1) rl = (long)N - 1;
        const unsigned short* ap = hb + rl * HID + q * 8;
#pragma unroll
        for (int kb = 0; kb < 4; ++kb)
            a[kb] = *reinterpret_cast<const short8*>(ap + kb * 32);
    }

    floatx4 acc[8];
#pragma unroll
    for (int nt = 0; nt < 8; ++nt) {
        floatx4 zz = {0.f, 0.f, 0.f, 0.f};
        acc[nt] = zz;
    }

#pragma unroll
    for (int nt = 0; nt < 8; ++nt) {
        const unsigned short* bp = Wb + (nt * 16 + l15) * HID + q * 8;
#pragma unroll
        for (int kb = 0; kb < 4; ++kb) {
            short8 b = *reinterpret_cast<const short8*>(bp + kb * 32);
            acc[nt] = __builtin_amdgcn_mfma_f32_16x16x32_bf16(a[kb], b, acc[nt], 0, 0, 0);
        }
    }

    float bi[8];
#pragma unroll
    for (int nt = 0; nt < 8; ++nt) bi[nt] = bias[nt * 16 + l15];

    // C-restage: row = q*4 + r (within wave's 16-row tile), col = l15 + 16*nt
#pragma unroll
    for (int r = 0; r < 4; ++r) {
        int lr = wave * 16 + q * 4 + r;
#pragma unroll
        for (int nt = 0; nt < 8; ++nt)
            st[lr][l15 + 16 * nt] = f2bf(acc[nt][r] + bi[nt]);
    }
    __syncthreads();

    // coalesced store: 256 threads x 16B = 16 rows/iter, 4 iters
    int tr = tid >> 4;
    int tc = (tid & 15) * 8;
#pragma unroll
    for (int i = 0; i < 4; ++i) {
        int row = i * 16 + tr;
        long gr = base + row;
        if (gr < N) {
            ushort8v v = *reinterpret_cast<const ushort8v*>(&st[row][tc]);
            *reinterpret_cast<ushort8v*>(zb + gr * HID + tc) = v;
        }
    }
}

// ---------------- fused encode + gemm#1 (64-row tile) ----------------
__global__ __launch_bounds__(256) void egemm_kernel(
    const int* __restrict__ x, const float* __restrict__ atom_emb,
    const unsigned short* __restrict__ Wb, const float* __restrict__ bias,
    unsigned short* __restrict__ zb, int N)
{
    __shared__ unsigned short hs[64][132];
    int tid = threadIdx.x;
    long base = (long)blockIdx.x * 64;
    const int OFF[9] = {0, 119, 123, 135, 147, 157, 163, 169, 171};

    // phase A: embedding sums, 16 nodes/pass x 4 passes
    int sn = tid >> 4;
    int cc = (tid & 15) * 8;
#pragma unroll 1
    for (int s = 0; s < 4; ++s) {
        int lr = s * 16 + sn;
        long n = base + lr;
        ushort8v o;
        if (n < N) {
            float acc[8];
#pragma unroll
            for (int j = 0; j < 8; ++j) acc[j] = 0.f;
#pragma unroll
            for (int f = 0; f < 9; ++f) {
                int idx = x[n * 9 + f] + OFF[f];
                const float* ep = atom_emb + (long)idx * HID + cc;
                floatx4 v0 = *reinterpret_cast<const floatx4*>(ep);
                floatx4 v1 = *reinterpret_cast<const floatx4*>(ep + 4);
#pragma unroll
                for (int j = 0; j < 4; ++j) { acc[j] += v0[j]; acc[j + 4] += v1[j]; }
            }
#pragma unroll
            for (int j = 0; j < 8; ++j) o[j] = f2bf(acc[j]);
        } else {
            ushort8v z8 = {0, 0, 0, 0, 0, 0, 0, 0};
            o = z8;
        }
        *reinterpret_cast<ushort8v*>(&hs[lr][cc]) = o;
    }
    __syncthreads();

    // phase B: MFMA (1 m-tile/wave)
    int wave = tid >> 6;
    int lane = tid & 63;
    int l15 = lane & 15;
    int q = lane >> 4;

    short8 a[4];
    {
        int rl = wave * 16 + l15;
#pragma unroll
        for (int kb = 0; kb < 4; ++kb)
            a[kb] = *reinterpret_cast<const short8*>(&hs[rl][q * 8 + kb * 32]);
    }

    floatx4 acc[8];
#pragma unroll
    for (int nt = 0; nt < 8; ++nt) {
        floatx4 zz = {0.f, 0.f, 0.f, 0.f};
        acc[nt] = zz;
    }

#pragma unroll
    for (int nt = 0; nt < 8; ++nt) {
        const unsigned short* bp = Wb + (nt * 16 + l15) * HID + q * 8;
#pragma unroll
        for (int kb = 0; kb < 4; ++kb) {
            short8 b = *reinterpret_cast<const short8*>(bp + kb * 32);
            acc[nt] = __builtin_amdgcn_mfma_f32_16x16x32_bf16(a[kb], b, acc[nt], 0, 0, 0);
        }
    }

    float bi[8];
#pragma unroll
    for (int nt = 0; nt < 8; ++nt) bi[nt] = bias[nt * 16 + l15];

    __syncthreads();
#pragma unroll
    for (int r = 0; r < 4; ++r) {
        int lr = wave * 16 + q * 4 + r;
#pragma unroll
        for (int nt = 0; nt < 8; ++nt)
            hs[lr][l15 + 16 * nt] = f2bf(acc[nt][r] + bi[nt]);
    }
    __syncthreads();

    int tr = tid >> 4;
    int tc = (tid & 15) * 8;
#pragma unroll
    for (int i = 0; i < 4; ++i) {
        int row = i * 16 + tr;
        long gr = base + row;
        if (gr < N) {
            ushort8v v = *reinterpret_cast<const ushort8v*>(&hs[row][tc]);
            *reinterpret_cast<ushort8v*>(zb + gr * HID + tc) = v;
        }
    }
}

// ---------------- final linear via MFMA (G small; direct fp32 store) ---------
__global__ __launch_bounds__(256) void linmm_kernel(
    const unsigned short* __restrict__ pb, const unsigned short* __restrict__ Wb,
    const float* __restrict__ bias, float* __restrict__ out, int G)
{
    int wave = threadIdx.x >> 6;
    int lane = threadIdx.x & 63;
    int l15 = lane & 15;
    int q = lane >> 4;
    long row0 = (long)blockIdx.x * 64 + wave * 16;

    short8 a[4];
    {
        long rl = row0 + l15;
        if (rl > (long)G - 1) rl = (long)G - 1;
        const unsigned short* ap = pb + rl * HID + q * 8;
#pragma unroll
        for (int kb = 0; kb < 4; ++kb)
            a[kb] = *reinterpret_cast<const short8*>(ap + kb * 32);
    }

    floatx4 acc[8];
#pragma unroll
    for (int nt = 0; nt < 8; ++nt) {
        floatx4 zz = {0.f, 0.f, 0.f, 0.f};
        acc[nt] = zz;
    }

#pragma unroll
    for (int nt = 0; nt < 8; ++nt) {
        const unsigned short* bp = Wb + (nt * 16 + l15) * HID + q * 8;
#pragma unroll
        for (int kb = 0; kb < 4; ++kb) {
            short8 b = *reinterpret_cast<const short8*>(bp + kb * 32);
            acc[nt] = __builtin_amdgcn_mfma_f32_16x16x32_bf16(a[kb], b, acc[nt], 0, 0, 0);
        }
    }

    float bi[8];
#pragma unroll
    for (int nt = 0; nt < 8; ++nt) bi[nt] = bias[nt * 16 + l15];

#pragma unroll
    for (int r = 0; r < 4; ++r) {
        long rr = row0 + q * 4 + r;
        if (rr < G) {
            float* op = out + rr * HID + l15;
#pragma unroll
            for (int nt = 0; nt < 8; ++nt)
                op[nt * 16] = acc[nt][r] + bi[nt];
        }
    }
}

// ---------------- mean-pool per graph -> bf16 pooled[G][128] ----------------
__global__ __launch_bounds__(256) void pool_kernel(
    const unsigned short* __restrict__ hb, const int* __restrict__ gptr,
    unsigned short* __restrict__ pb, int G)
{
    int g = blockIdx.x;
    if (g >= G) return;
    int tid = threadIdx.x;
    int sub = tid >> 5;
    int c = (tid & 31) * 4;
    int lo = gptr[g], hi = gptr[g + 1];
    floatx4 s = {0.f, 0.f, 0.f, 0.f};
    for (int n = lo + sub; n < hi; n += 8) {
        ushort4v hv = *reinterpret_cast<const ushort4v*>(hb + (long)n * HID + c);
#pragma unroll
        for (int j = 0; j < 4; ++j) s[j] += bf2f(hv[j]);
    }
    __shared__ float ps[8][HID];
    *reinterpret_cast<floatx4*>(&ps[sub][c]) = s;
    __syncthreads();
    if (tid < HID) {
        float sum = 0.f;
#pragma unroll
        for (int k = 0; k < 8; ++k) sum += ps[k][tid];
        float cnt = (hi > lo) ? (float)(hi - lo) : 1.f;
        pb[(long)g * HID + tid] = f2bf(sum / cnt);
    }
}

extern "C" void kernel_launch(void* const* d_in, const int* in_sizes, int n_in,
                              void* d_out, int out_size, void* d_ws, size_t ws_size,
                              hipStream_t stream)
{
    const int* x          = (const int*)d_in[0];
    const int* ei         = (const int*)d_in[1];
    const int* attr       = (const int*)d_in[2];
    const int* batch      = (const int*)d_in[3];
    const float* atom_emb = (const float*)d_in[4];
    const float* bond_emb = (const float*)d_in[5];
    const float* conv_W   = (const float*)d_in[6];
    const float* conv_b   = (const float*)d_in[7];
    const float* root     = (const float*)d_in[8];
    const float* gamma    = (const float*)d_in[9];
    const float* beta     = (const float*)d_in[10];
    const float* mean     = (const float*)d_in[11];
    const float* var      = (const float*)d_in[12];
    const float* lin_W    = (const float*)d_in[13];
    const float* lin_b    = (const float*)d_in[14];
    float* out = (float*)d_out;

    const int N = in_sizes[0] / 9;
    const int E = in_sizes[1] / 2;
    const int G = out_size / HID;
    const int B = (N + 255) / 256;

    auto al = [](size_t b) { return (b + 255) & ~(size_t)255; };
    const size_t need =
        al((size_t)N * HID * 2) +         // hb
        al((size_t)N * HID * 2) +         // zb
        al((size_t)(N + 1) * 4) +         // ptr
        al((size_t)E * 8) +               // edata (int2)
        al((size_t)N * 4) +               // indeg (= cursor)
        al((size_t)2048 * 4) * 2 +        // partial + offs
        al((size_t)(G + 1) * 4) +         // gptr
        al((size_t)(G + 128) * HID * 2) + // pooled bf16 (dis aliases; +tail pad)
        al((size_t)60 * HID * 4) +        // comb
        al((size_t)HID * 4) * 2 +         // bnsc + bnsh
        al((size_t)HID * HID * 2) * 2;    // Wb + linWb

    if (ws_size < need || B > 2048) {
        float v = (B > 2048) ? 3000.f : (1000.f + (float)(ws_size >> 20));
        long n = (long)out_size;
        diag_kernel<<<(int)((n + 255) / 256), 256, 0, stream>>>(out, n, v);
        return;
    }

    char* wsp = (char*)d_ws;
    size_t used = 0;
    auto alloc = [&](size_t bytes) { char* p = wsp + used; used += al(bytes); return p; };
    unsigned short* hb = (unsigned short*)alloc((size_t)N * HID * 2);
    unsigned short* zb = (unsigned short*)alloc((size_t)N * HID * 2);
    int* ptr      = (int*)alloc((size_t)(N + 1) * 4);
    int2* edata   = (int2*)alloc((size_t)E * 8);
    int* indeg    = (int*)alloc((size_t)N * 4);
    int* cursor   = indeg;
    int* partial  = (int*)alloc((size_t)2048 * 4);
    int* offs     = (int*)alloc((size_t)2048 * 4);
    int* gptr     = (int*)alloc((size_t)(G + 1) * 4);
    unsigned short* pb = (unsigned short*)alloc((size_t)(G + 128) * HID * 2);
    float* dis    = (float*)pb;               // alias: dis dead before pool writes pb
    float* comb   = (float*)alloc((size_t)60 * HID * 4);
    float* bnsc   = (float*)alloc((size_t)HID * 4);
    float* bnsh   = (float*)alloc((size_t)HID * 4);
    unsigned short* Wb    = (unsigned short*)alloc((size_t)HID * HID * 2);
    unsigned short* linWb = (unsigned short*)alloc((size_t)HID * HID * 2);

    // ---- prologue ----
    fillrd_kernel<<<B, 256, 0, stream>>>(dis, indeg, N);
    tables_kernel<<<159, 256, 0, stream>>>(conv_W, Wb, lin_W, linWb, bond_emb, comb,
                                           gamma, beta, mean, var, bnsc, bnsh);
    hist_kernel<<<1024, 256, 0, stream>>>(ei, dis, indeg, E);
    fdeg_kernel<<<B, 256, 0, stream>>>(dis, N);
    bsum_kernel<<<B, 256, 0, stream>>>(indeg, partial, N);
    scan1_kernel<<<1, 256, 0, stream>>>(partial, offs, ptr, B, N);
    scan2_kernel<<<B, 256, 0, stream>>>(indeg, offs, ptr, cursor, N);
    fillcsr_kernel<<<1024, 256, 0, stream>>>(ei, attr, dis, cursor, edata, E);
    gptr_kernel<<<B, 256, 0, stream>>>(batch, gptr, N, G);

    // ---- loop (i=1 identity, skipped; fis = {0,2,3,4}) ----
    const int gemm_blocks = (N + 63) / 64;
    const int agg_blocks  = (N + 15) / 16;
    egemm_kernel<<<gemm_blocks, 256, 0, stream>>>(x, atom_emb, Wb, conv_b, zb, N);
    agg_kernel<true ><<<agg_blocks, 256, 0, stream>>>(ptr, edata, comb, dis, root,
            bnsc, bnsh, zb, hb, 0.f, N);
    const float fis[3] = {2.f, 3.f, 4.f};
    for (int t = 0; t < 3; ++t) {
        gemm_kernel<<<gemm_blocks, 256, 0, stream>>>(hb, Wb, conv_b, zb, N);
        agg_kernel<false><<<agg_blocks, 256, 0, stream>>>(ptr, edata, comb, dis, root,
                bnsc, bnsh, zb, hb, fis[t], N);
    }

    // ---- mean-pool (bf16) + MFMA final linear (fp32 out) ----
    pool_kernel<<<G, 256, 0, stream>>>(hb, gptr, pb, G);
    linmm_kernel<<<(G + 63) / 64, 256, 0, stream>>>(pb, linWb, lin_b, out, G);
}

// Round 14
// 728.659 us; speedup vs baseline: 1.1243x; 1.1243x over previous
//
#include <hip/hip_runtime.h>

#define HID 128

typedef __attribute__((ext_vector_type(8))) short short8;
typedef __attribute__((ext_vector_type(8))) unsigned short ushort8v;
typedef __attribute__((ext_vector_type(4))) float floatx4;
typedef __attribute__((ext_vector_type(4))) unsigned short ushort4v;

__device__ __forceinline__ unsigned short f2bf(float f) {
    unsigned u = __builtin_bit_cast(unsigned, f);
    u += 0x7FFF + ((u >> 16) & 1);           // RNE
    return (unsigned short)(u >> 16);
}
__device__ __forceinline__ float bf2f(unsigned short s) {
    unsigned u = ((unsigned)s) << 16;
    return __builtin_bit_cast(float, u);
}

// ---------------- diagnostic ----------------
__global__ void diag_kernel(float* __restrict__ out, long n, float val)
{
    long i = (long)blockIdx.x * blockDim.x + threadIdx.x;
    if (i < n) out[i] = val;
}

// ---------------- merged prep: fills + tables + BN fold + gptr ---------------
// blocks [0,B): zero dis/indeg | [B,B+64): Wb | [B+64,B+128): linWb
// [B+128,B+158): comb | B+158: BN fold | [B+159, 2B+159): gptr
__global__ __launch_bounds__(256) void prep_kernel(
    float* __restrict__ dis, int* __restrict__ indeg, int N,
    const float* __restrict__ conv_W, unsigned short* __restrict__ Wb,
    const float* __restrict__ lin_W, unsigned short* __restrict__ linWb,
    const float* __restrict__ bond_emb, float* __restrict__ comb,
    const float* __restrict__ gamma, const float* __restrict__ beta,
    const float* __restrict__ mean, const float* __restrict__ var,
    float* __restrict__ bnsc, float* __restrict__ bnsh,
    const int* __restrict__ batch, int* __restrict__ gptr, int G, int B)
{
    int blk = blockIdx.x;
    int tid = threadIdx.x;
    if (blk < B) {
        int i = blk * 256 + tid;
        if (i < N) { dis[i] = 0.f; indeg[i] = 0; }
    } else if (blk < B + 64) {
        int i = (blk - B) * 256 + tid;
        Wb[i] = f2bf(conv_W[i]);
    } else if (blk < B + 128) {
        int i = (blk - B - 64) * 256 + tid;
        linWb[i] = f2bf(lin_W[i]);
    } else if (blk < B + 158) {
        int i = (blk - B - 128) * 2 + (tid >> 7);
        int c = tid & 127;
        int a0 = i / 12, a1 = (i % 12) / 2, a2 = i % 2;
        comb[i * HID + c] = bond_emb[a0 * HID + c] + bond_emb[(5 + a1) * HID + c]
                          + bond_emb[(11 + a2) * HID + c];
    } else if (blk == B + 158) {
        if (tid < HID) {
            float sc = gamma[tid] * rsqrtf(var[tid] + 1e-5f);
            bnsc[tid] = sc;
            bnsh[tid] = beta[tid] - mean[tid] * sc;
        }
    } else {
        int n = (blk - B - 159) * 256 + tid;
        if (n < N) {
            int b = batch[n];
            int bp = (n == 0) ? -1 : batch[n - 1];
            for (int g = bp + 1; g <= b; ++g) gptr[g] = n;
            if (n == N - 1)
                for (int g = b + 1; g <= G; ++g) gptr[g] = N;
        }
    }
}

// ---------------- merged degree histograms ----------------
__global__ void hist_kernel(const int* __restrict__ ei, float* __restrict__ dis,
                            int* __restrict__ indeg, int E)
{
    for (int e = blockIdx.x * blockDim.x + threadIdx.x; e < E; e += gridDim.x * blockDim.x) {
        atomicAdd(&dis[ei[e]], 1.f);
        atomicAdd(&indeg[ei[E + e]], 1);
    }
}

// ---------------- merged: fdeg (dis -> deg^-0.5) + bsum (indeg partials) -----
__global__ __launch_bounds__(256) void postdeg_kernel(
    float* __restrict__ dis, const int* __restrict__ indeg,
    int* __restrict__ partial, int N)
{
    __shared__ int s[256];
    int i = blockIdx.x * 256 + threadIdx.x;
    if (i < N) dis[i] = rsqrtf(dis[i] + 1.f);
    s[threadIdx.x] = (i < N) ? indeg[i] : 0;
    __syncthreads();
    for (int d = 128; d > 0; d >>= 1) {
        if (threadIdx.x < d) s[threadIdx.x] += s[threadIdx.x + d];
        __syncthreads();
    }
    if (threadIdx.x == 0) partial[blockIdx.x] = s[0];
}

__global__ __launch_bounds__(256) void scan1_kernel(
    const int* __restrict__ partial, int* __restrict__ offs,
    int* __restrict__ ptr, int B, int N)
{
    __shared__ int s[256];
    __shared__ int carry_s;
    int tid = threadIdx.x;
    if (tid == 0) carry_s = 0;
    __syncthreads();
    for (int base = 0; base < B; base += 256) {
        int i = base + tid;
        int v = (i < B) ? partial[i] : 0;
        s[tid] = v;
        __syncthreads();
        for (int d = 1; d < 256; d <<= 1) {
            int t = (tid >= d) ? s[tid - d] : 0;
            __syncthreads();
            s[tid] += t;
            __syncthreads();
        }
        int carry = carry_s;
        if (i < B) offs[i] = carry + s[tid] - v;
        __syncthreads();
        if (tid == 0) carry_s = carry + s[255];
        __syncthreads();
    }
    if (tid == 0) ptr[N] = carry_s;
}

// in-place safe: cursor may alias indeg
__global__ __launch_bounds__(256) void scan2_kernel(
    const int* __restrict__ indeg, const int* __restrict__ offs,
    int* __restrict__ ptr, int* __restrict__ cursor, int N)
{
    __shared__ int s[256];
    int tid = threadIdx.x;
    int i = blockIdx.x * 256 + tid;
    int v = (i < N) ? indeg[i] : 0;
    s[tid] = v;
    __syncthreads();
    for (int d = 1; d < 256; d <<= 1) {
        int t = (tid >= d) ? s[tid - d] : 0;
        __syncthreads();
        s[tid] += t;
        __syncthreads();
    }
    if (i < N) {
        int ex = offs[blockIdx.x] + s[tid] - v;
        ptr[i] = ex;
        cursor[i] = ex;
    }
}

// ---------------- CSR fill: packed edge record ----------------
__global__ void fillcsr_kernel(const int* __restrict__ ei, const int* __restrict__ attr,
                               const float* __restrict__ dis, int* __restrict__ cursor,
                               int2* __restrict__ edata, int E)
{
    for (int e = blockIdx.x * blockDim.x + threadIdx.x; e < E; e += gridDim.x * blockDim.x) {
        int r   = ei[e];
        int col = ei[E + e];
        int pos = atomicAdd(&cursor[col], 1);
        int ci  = attr[e * 3] * 12 + attr[e * 3 + 1] * 2 + attr[e * 3 + 2];
        float nrm = dis[r] * dis[col];
        int2 ed;
        ed.x = r;
        ed.y = ci | ((int)f2bf(nrm) << 16);
        edata[pos] = ed;
    }
}

// ---------------- shared agg body ----------------
template<bool FIRST>
__device__ __forceinline__ ushort8v agg_node(
    long n, int c, const int* __restrict__ ptr, const int2* __restrict__ edata,
    const float* __restrict__ comb, const float* __restrict__ dis,
    const float* __restrict__ root, const float* __restrict__ bnsc,
    const float* __restrict__ bnsh, const unsigned short* __restrict__ zb,
    const unsigned short* __restrict__ hb, float fi)
{
    ushort8v zv = *reinterpret_cast<const ushort8v*>(zb + n * HID + c);
    ushort8v hv;
    if constexpr (!FIRST) hv = *reinterpret_cast<const ushort8v*>(hb + n * HID + c);
    float di = dis[n];
    float rd = di * di;
    float acc[8];
#pragma unroll
    for (int j = 0; j < 8; ++j) acc[j] = fmaxf(bf2f(zv[j]) + root[c + j], 0.f) * rd;

    int jb = ptr[n], je = ptr[n + 1];
    int j2 = jb;
    for (; j2 + 1 < je; j2 += 2) {
        int2 e0 = edata[j2];
        int2 e1 = edata[j2 + 1];
        ushort8v z0 = *reinterpret_cast<const ushort8v*>(zb + (long)e0.x * HID + c);
        ushort8v z1 = *reinterpret_cast<const ushort8v*>(zb + (long)e1.x * HID + c);
        const float* c0 = comb + (e0.y & 0xFF) * HID + c;
        const float* c1 = comb + (e1.y & 0xFF) * HID + c;
        float n0 = bf2f((unsigned short)(((unsigned)e0.y) >> 16));
        float n1 = bf2f((unsigned short)(((unsigned)e1.y) >> 16));
#pragma unroll
        for (int j = 0; j < 8; ++j) {
            acc[j] += fmaxf(bf2f(z0[j]) + c0[j], 0.f) * n0;
            acc[j] += fmaxf(bf2f(z1[j]) + c1[j], 0.f) * n1;
        }
    }
    if (j2 < je) {
        int2 e0 = edata[j2];
        ushort8v z0 = *reinterpret_cast<const ushort8v*>(zb + (long)e0.x * HID + c);
        const float* c0 = comb + (e0.y & 0xFF) * HID + c;
        float n0 = bf2f((unsigned short)(((unsigned)e0.y) >> 16));
#pragma unroll
        for (int j = 0; j < 8; ++j) acc[j] += fmaxf(bf2f(z0[j]) + c0[j], 0.f) * n0;
    }

    ushort8v o;
#pragma unroll
    for (int j = 0; j < 8; ++j) {
        float t = fmaxf(acc[j], 0.f) * bnsc[c + j] + bnsh[c + j];
        float h;
        if constexpr (FIRST) h = t;
        else h = fi * bf2f(hv[j]) + (1.f - fi) * t;
        o[j] = f2bf(h);
    }
    return o;
}

// ---------------- standalone agg (high-occupancy gather loop) ----------------
template<bool FIRST>
__global__ __launch_bounds__(256) void agg_kernel(
    const int* __restrict__ ptr, const int2* __restrict__ edata,
    const float* __restrict__ comb, const float* __restrict__ dis,
    const float* __restrict__ root, const float* __restrict__ bnsc,
    const float* __restrict__ bnsh, const unsigned short* __restrict__ zb,
    unsigned short* __restrict__ hb, float fi, int N)
{
    long n = (long)blockIdx.x * 16 + (threadIdx.x >> 4);
    if (n >= N) return;
    int c = (threadIdx.x & 15) * 8;
    ushort8v o = agg_node<FIRST>(n, c, ptr, edata, comb, dis, root, bnsc, bnsh, zb, hb, fi);
    *reinterpret_cast<ushort8v*>(hb + n * HID + c) = o;
}

// ---------------- z = h @ W^T + b  (128-row block, wave-private restage, ------
// NO barriers: wave w owns rows [32w,32w+32), restages in its own LDS region)
__global__ __launch_bounds__(256) void gemm_kernel(
    const unsigned short* __restrict__ hb, const unsigned short* __restrict__ Wb,
    const float* __restrict__ bias, unsigned short* __restrict__ zb, int N)
{
    __shared__ unsigned short st[4][32][144];   // stride 144 ushorts = 72 words ≡ 8 banks
    int tid = threadIdx.x;
    int wave = tid >> 6;
    int lane = tid & 63;
    int l15 = lane & 15;
    int q = lane >> 4;
    long row0 = (long)blockIdx.x * 128 + wave * 32;

    short8 a[2][4];
#pragma unroll
    for (int mt = 0; mt < 2; ++mt) {
        long rl = row0 + mt * 16 + l15;
        if (rl > (long)N - 1) rl = (long)N - 1;
        const unsigned short* ap = hb + rl * HID + q * 8;
#pragma unroll
        for (int kb = 0; kb < 4; ++kb)
            a[mt][kb] = *reinterpret_cast<const short8*>(ap + kb * 32);
    }

    floatx4 acc[2][8];
#pragma unroll
    for (int mt = 0; mt < 2; ++mt)
#pragma unroll
        for (int nt = 0; nt < 8; ++nt) {
            floatx4 zz = {0.f, 0.f, 0.f, 0.f};
            acc[mt][nt] = zz;
        }

#pragma unroll
    for (int nt = 0; nt < 8; ++nt) {
        const unsigned short* bp = Wb + (nt * 16 + l15) * HID + q * 8;
#pragma unroll
        for (int kb = 0; kb < 4; ++kb) {
            short8 b = *reinterpret_cast<const short8*>(bp + kb * 32);
            acc[0][nt] = __builtin_amdgcn_mfma_f32_16x16x32_bf16(a[0][kb], b, acc[0][nt], 0, 0, 0);
            acc[1][nt] = __builtin_amdgcn_mfma_f32_16x16x32_bf16(a[1][kb], b, acc[1][nt], 0, 0, 0);
        }
    }

    float bi[8];
#pragma unroll
    for (int nt = 0; nt < 8; ++nt) bi[nt] = bias[nt * 16 + l15];

    // wave-private restage (rows local to this wave; no __syncthreads needed)
#pragma unroll
    for (int mt = 0; mt < 2; ++mt)
#pragma unroll
        for (int r = 0; r < 4; ++r) {
            int lr = mt * 16 + q * 4 + r;
#pragma unroll
            for (int nt = 0; nt < 8; ++nt)
                st[wave][lr][l15 + 16 * nt] = f2bf(acc[mt][nt][r] + bi[nt]);
        }

    // coalesced store of this wave's 32 rows: 8 iters x (4 rows x 256B = 1KB)
#pragma unroll
    for (int it = 0; it < 8; ++it) {
        int lr = it * 4 + q;
        long gr = row0 + lr;
        if (gr < N) {
            ushort8v v = *reinterpret_cast<const ushort8v*>(&st[wave][lr][l15 * 8]);
            *reinterpret_cast<ushort8v*>(zb + gr * HID + l15 * 8) = v;
        }
    }
}

// ---------------- fused encode + gemm#1 (wave-private, barrier-free) ---------
__global__ __launch_bounds__(256) void egemm_kernel(
    const int* __restrict__ x, const float* __restrict__ atom_emb,
    const unsigned short* __restrict__ Wb, const float* __restrict__ bias,
    unsigned short* __restrict__ zb, int N)
{
    __shared__ unsigned short st[4][32][144];
    int tid = threadIdx.x;
    int wave = tid >> 6;
    int lane = tid & 63;
    int l15 = lane & 15;
    int q = lane >> 4;
    long row0 = (long)blockIdx.x * 128 + wave * 32;
    const int OFF[9] = {0, 119, 123, 135, 147, 157, 163, 169, 171};

    // phase A (wave-private): 8 passes x 4 nodes (16 lanes/node)
    int cc = l15 * 8;
#pragma unroll 1
    for (int s = 0; s < 8; ++s) {
        int lr = s * 4 + q;
        long n = row0 + lr;
        ushort8v o;
        if (n < N) {
            float acc[8];
#pragma unroll
            for (int j = 0; j < 8; ++j) acc[j] = 0.f;
#pragma unroll
            for (int f = 0; f < 9; ++f) {
                int idx = x[n * 9 + f] + OFF[f];
                const float* ep = atom_emb + (long)idx * HID + cc;
                floatx4 v0 = *reinterpret_cast<const floatx4*>(ep);
                floatx4 v1 = *reinterpret_cast<const floatx4*>(ep + 4);
#pragma unroll
                for (int j = 0; j < 4; ++j) { acc[j] += v0[j]; acc[j + 4] += v1[j]; }
            }
#pragma unroll
            for (int j = 0; j < 8; ++j) o[j] = f2bf(acc[j]);
        } else {
            ushort8v z8 = {0, 0, 0, 0, 0, 0, 0, 0};
            o = z8;
        }
        *reinterpret_cast<ushort8v*>(&st[wave][lr][cc]) = o;
    }
    // no barrier: this wave's A rows are entirely its own

    short8 a[2][4];
#pragma unroll
    for (int mt = 0; mt < 2; ++mt) {
        int rl = mt * 16 + l15;
#pragma unroll
        for (int kb = 0; kb < 4; ++kb)
            a[mt][kb] = *reinterpret_cast<const short8*>(&st[wave][rl][q * 8 + kb * 32]);
    }

    floatx4 acc[2][8];
#pragma unroll
    for (int mt = 0; mt < 2; ++mt)
#pragma unroll
        for (int nt = 0; nt < 8; ++nt) {
            floatx4 zz = {0.f, 0.f, 0.f, 0.f};
            acc[mt][nt] = zz;
        }

#pragma unroll
    for (int nt = 0; nt < 8; ++nt) {
        const unsigned short* bp = Wb + (nt * 16 + l15) * HID + q * 8;
#pragma unroll
        for (int kb = 0; kb < 4; ++kb) {
            short8 b = *reinterpret_cast<const short8*>(bp + kb * 32);
            acc[0][nt] = __builtin_amdgcn_mfma_f32_16x16x32_bf16(a[0][kb], b, acc[0][nt], 0, 0, 0);
            acc[1][nt] = __builtin_amdgcn_mfma_f32_16x16x32_bf16(a[1][kb], b, acc[1][nt], 0, 0, 0);
        }
    }

    float bi[8];
#pragma unroll
    for (int nt = 0; nt < 8; ++nt) bi[nt] = bias[nt * 16 + l15];

    // wave-private C restage (A-fragments already consumed into registers)
#pragma unroll
    for (int mt = 0; mt < 2; ++mt)
#pragma unroll
        for (int r = 0; r < 4; ++r) {
            int lr = mt * 16 + q * 4 + r;
#pragma unroll
            for (int nt = 0; nt < 8; ++nt)
                st[wave][lr][l15 + 16 * nt] = f2bf(acc[mt][nt][r] + bi[nt]);
        }

#pragma unroll
    for (int it = 0; it < 8; ++it) {
        int lr = it * 4 + q;
        long gr = row0 + lr;
        if (gr < N) {
            ushort8v v = *reinterpret_cast<const ushort8v*>(&st[wave][lr][l15 * 8]);
            *reinterpret_cast<ushort8v*>(zb + gr * HID + l15 * 8) = v;
        }
    }
}

// ---------------- final linear via MFMA (fp32 direct store) ------------------
__global__ __launch_bounds__(256) void linmm_kernel(
    const unsigned short* __restrict__ pb, const unsigned short* __restrict__ Wb,
    const float* __restrict__ bias, float* __restrict__ out, int G)
{
    int wave = threadIdx.x >> 6;
    int lane = threadIdx.x & 63;
    int l15 = lane & 15;
    int q = lane >> 4;
    long row0 = (long)blockIdx.x * 128 + wave * 32;

    short8 a[2][4];
#pragma unroll
    for (int mt = 0; mt < 2; ++mt) {
        long rl = row0 + mt * 16 + l15;
        if (rl > (long)G - 1) rl = (long)G - 1;
        const unsigned short* ap = pb + rl * HID + q * 8;
#pragma unroll
        for (int kb = 0; kb < 4; ++kb)
            a[mt][kb] = *reinterpret_cast<const short8*>(ap + kb * 32);
    }

    floatx4 acc[2][8];
#pragma unroll
    for (int mt = 0; mt < 2; ++mt)
#pragma unroll
        for (int nt = 0; nt < 8; ++nt) {
            floatx4 zz = {0.f, 0.f, 0.f, 0.f};
            acc[mt][nt] = zz;
        }

#pragma unroll
    for (int nt = 0; nt < 8; ++nt) {
        const unsigned short* bp = Wb + (nt * 16 + l15) * HID + q * 8;
#pragma unroll
        for (int kb = 0; kb < 4; ++kb) {
            short8 b = *reinterpret_cast<const short8*>(bp + kb * 32);
            acc[0][nt] = __builtin_amdgcn_mfma_f32_16x16x32_bf16(a[0][kb], b, acc[0][nt], 0, 0, 0);
            acc[1][nt] = __builtin_amdgcn_mfma_f32_16x16x32_bf16(a[1][kb], b, acc[1][nt], 0, 0, 0);
        }
    }

    float bi[8];
#pragma unroll
    for (int nt = 0; nt < 8; ++nt) bi[nt] = bias[nt * 16 + l15];

#pragma unroll
    for (int mt = 0; mt < 2; ++mt)
#pragma unroll
        for (int r = 0; r < 4; ++r) {
            long rr = row0 + mt * 16 + q * 4 + r;
            if (rr < G) {
                float* op = out + rr * HID + l15;
#pragma unroll
                for (int nt = 0; nt < 8; ++nt)
                    op[nt * 16] = acc[mt][nt][r] + bi[nt];
            }
        }
}

// ---------------- mean-pool per graph -> bf16 pooled[G][128] ----------------
__global__ __launch_bounds__(256) void pool_kernel(
    const unsigned short* __restrict__ hb, const int* __restrict__ gptr,
    unsigned short* __restrict__ pb, int G)
{
    int g = blockIdx.x;
    if (g >= G) return;
    int tid = threadIdx.x;
    int sub = tid >> 5;
    int c = (tid & 31) * 4;
    int lo = gptr[g], hi = gptr[g + 1];
    floatx4 s = {0.f, 0.f, 0.f, 0.f};
    for (int n = lo + sub; n < hi; n += 8) {
        ushort4v hv = *reinterpret_cast<const ushort4v*>(hb + (long)n * HID + c);
#pragma unroll
        for (int j = 0; j < 4; ++j) s[j] += bf2f(hv[j]);
    }
    __shared__ float ps[8][HID];
    *reinterpret_cast<floatx4*>(&ps[sub][c]) = s;
    __syncthreads();
    if (tid < HID) {
        float sum = 0.f;
#pragma unroll
        for (int k = 0; k < 8; ++k) sum += ps[k][tid];
        float cnt = (hi > lo) ? (float)(hi - lo) : 1.f;
        pb[(long)g * HID + tid] = f2bf(sum / cnt);
    }
}

extern "C" void kernel_launch(void* const* d_in, const int* in_sizes, int n_in,
                              void* d_out, int out_size, void* d_ws, size_t ws_size,
                              hipStream_t stream)
{
    const int* x          = (const int*)d_in[0];
    const int* ei         = (const int*)d_in[1];
    const int* attr       = (const int*)d_in[2];
    const int* batch      = (const int*)d_in[3];
    const float* atom_emb = (const float*)d_in[4];
    const float* bond_emb = (const float*)d_in[5];
    const float* conv_W   = (const float*)d_in[6];
    const float* conv_b   = (const float*)d_in[7];
    const float* root     = (const float*)d_in[8];
    const float* gamma    = (const float*)d_in[9];
    const float* beta     = (const float*)d_in[10];
    const float* mean     = (const float*)d_in[11];
    const float* var      = (const float*)d_in[12];
    const float* lin_W    = (const float*)d_in[13];
    const float* lin_b    = (const float*)d_in[14];
    float* out = (float*)d_out;

    const int N = in_sizes[0] / 9;
    const int E = in_sizes[1] / 2;
    const int G = out_size / HID;
    const int B = (N + 255) / 256;

    auto al = [](size_t b) { return (b + 255) & ~(size_t)255; };
    const size_t need =
        al((size_t)N * HID * 2) +         // hb
        al((size_t)N * HID * 2) +         // zb
        al((size_t)(N + 1) * 4) +         // ptr
        al((size_t)E * 8) +               // edata (int2)
        al((size_t)N * 4) +               // indeg (= cursor)
        al((size_t)2048 * 4) * 2 +        // partial + offs
        al((size_t)(G + 1) * 4) +         // gptr
        al((size_t)(G + 128) * HID * 2) + // pooled bf16 (dis aliases; +tail pad)
        al((size_t)60 * HID * 4) +        // comb
        al((size_t)HID * 4) * 2 +         // bnsc + bnsh
        al((size_t)HID * HID * 2) * 2;    // Wb + linWb

    if (ws_size < need || B > 2048) {
        float v = (B > 2048) ? 3000.f : (1000.f + (float)(ws_size >> 20));
        long n = (long)out_size;
        diag_kernel<<<(int)((n + 255) / 256), 256, 0, stream>>>(out, n, v);
        return;
    }

    char* wsp = (char*)d_ws;
    size_t used = 0;
    auto alloc = [&](size_t bytes) { char* p = wsp + used; used += al(bytes); return p; };
    unsigned short* hb = (unsigned short*)alloc((size_t)N * HID * 2);
    unsigned short* zb = (unsigned short*)alloc((size_t)N * HID * 2);
    int* ptr      = (int*)alloc((size_t)(N + 1) * 4);
    int2* edata   = (int2*)alloc((size_t)E * 8);
    int* indeg    = (int*)alloc((size_t)N * 4);
    int* cursor   = indeg;
    int* partial  = (int*)alloc((size_t)2048 * 4);
    int* offs     = (int*)alloc((size_t)2048 * 4);
    int* gptr     = (int*)alloc((size_t)(G + 1) * 4);
    unsigned short* pb = (unsigned short*)alloc((size_t)(G + 128) * HID * 2);
    float* dis    = (float*)pb;               // alias: dis dead before pool writes pb
    float* comb   = (float*)alloc((size_t)60 * HID * 4);
    float* bnsc   = (float*)alloc((size_t)HID * 4);
    float* bnsh   = (float*)alloc((size_t)HID * 4);
    unsigned short* Wb    = (unsigned short*)alloc((size_t)HID * HID * 2);
    unsigned short* linWb = (unsigned short*)alloc((size_t)HID * HID * 2);

    // ---- prologue (6 dispatches) ----
    prep_kernel<<<2 * B + 159, 256, 0, stream>>>(dis, indeg, N, conv_W, Wb, lin_W, linWb,
                                                 bond_emb, comb, gamma, beta, mean, var,
                                                 bnsc, bnsh, batch, gptr, G, B);
    hist_kernel<<<1024, 256, 0, stream>>>(ei, dis, indeg, E);
    postdeg_kernel<<<B, 256, 0, stream>>>(dis, indeg, partial, N);
    scan1_kernel<<<1, 256, 0, stream>>>(partial, offs, ptr, B, N);
    scan2_kernel<<<B, 256, 0, stream>>>(indeg, offs, ptr, cursor, N);
    fillcsr_kernel<<<1024, 256, 0, stream>>>(ei, attr, dis, cursor, edata, E);

    // ---- loop (i=1 identity, skipped; fis = {0,2,3,4}) ----
    const int gemm_blocks = (N + 127) / 128;
    const int agg_blocks  = (N + 15) / 16;
    egemm_kernel<<<gemm_blocks, 256, 0, stream>>>(x, atom_emb, Wb, conv_b, zb, N);
    agg_kernel<true ><<<agg_blocks, 256, 0, stream>>>(ptr, edata, comb, dis, root,
            bnsc, bnsh, zb, hb, 0.f, N);
    const float fis[3] = {2.f, 3.f, 4.f};
    for (int t = 0; t < 3; ++t) {
        gemm_kernel<<<gemm_blocks, 256, 0, stream>>>(hb, Wb, conv_b, zb, N);
        agg_kernel<false><<<agg_blocks, 256, 0, stream>>>(ptr, edata, comb, dis, root,
                bnsc, bnsh, zb, hb, fis[t], N);
    }

    // ---- mean-pool (bf16) + MFMA final linear (fp32 out) ----
    pool_kernel<<<G, 256, 0, stream>>>(hb, gptr, pb, G);
    linmm_kernel<<<(G + 127) / 128, 256, 0, stream>>>(pb, linWb, lin_b, out, G);
}